// Round 12
// baseline (21080.789 us; speedup 1.0000x reference)
//
#include <hip/hip_runtime.h>

// ---------------------------------------------------------------------------
// SpikeRNN — r12: bisect r11's failure.
//  * einsum reverted VERBATIM to r10's proven intrinsic version (r11's v2f+
//    pragma variant may have been FMA-contracted -> ulp drift -> spike flips).
//  * pair-split rnn kept, hardened: mask stores/loads are RELEASE/ACQUIRE
//    agent-scope; spin cap 500K polls with timeout -> ws counter -> post-pass
//    check kernel writes sentinel 900+count into out[0] (diagnosable).
//  * h2 reads w_out_d from the d_out scored copy (bit-identical data).
// Numerics of all chains bit-identical to passing r7-r10.
// ---------------------------------------------------------------------------

constexpr int NB_IN  = 256;
constexpr int NB_REC = 1024;
constexpr int NB_OUT = 64;
constexpr int BATCH  = 128;
constexpr int NB_STEPS = 300;
constexpr int TSTEPS = NB_STEPS - 1;

constexpr float ALPHA_F = (float)0.8187307530779818;  // f32(exp(-0.2))
constexpr float BETA_F  = (float)0.9048374180359595;  // f32(exp(-0.1))

// d_out element offsets (f32 elements)
constexpr size_t OUT_REC_OFF = 0;
constexpr size_t SPK_REC_OFF = (size_t)BATCH * NB_STEPS * NB_OUT;
constexpr size_t WRECD_OFF   = SPK_REC_OFF + (size_t)BATCH * NB_STEPS * NB_REC;
constexpr size_t WOUTD_OFF   = WRECD_OFF + (size_t)NB_REC * NB_REC;
constexpr size_t WFF_OFF     = WOUTD_OFF + (size_t)NB_REC * NB_OUT;
constexpr int    OUT_TOTAL   = 43155456;

constexpr int SZ_INPUTS = BATCH * NB_STEPS * NB_IN;   // 9,830,400
constexpr int SZ_NOISE  = BATCH * NB_STEPS * NB_REC;  // 39,321,600
constexpr int SZ_WFF    = NB_IN * NB_REC;             // 262,144
constexpr int SZ_WREC   = NB_REC * NB_REC;            // 1,048,576
constexpr int SZ_WOUT   = NB_REC * NB_OUT;            // 65,536
constexpr int SZ_DSIGN  = NB_REC;                     // 1,024

constexpr int WREC_ROWS = NB_REC + 1;                 // +1 zero row (pad idx)
constexpr int N_FLAGS   = 512;                        // [0..255] flags, [256] tctr
constexpr int N_MASKW   = 2 * BATCH * 2 * 16;         // parity x batch x half x 16

__global__ void sentinel_kernel(float* out, float v) { out[0] = v; }

__global__ void check_kernel(const unsigned* tctr, float* out) {
  const unsigned c = *tctr;
  if (c) out[0] = 900.0f + (float)(c > 90u ? 90u : c);
}

// ---------------------------------------------------------------------------
// Dale weights -> ws f32 [1025,1024] (+zero row) and d_out copies; zero flags.
// ---------------------------------------------------------------------------
__global__ void weights_kernel(const float* __restrict__ w_rec,
                               const float* __restrict__ w_out,
                               const float* __restrict__ w_ff,
                               const float* __restrict__ d_sign,
                               float* __restrict__ f_wrecd,   // [1025,1024] ws
                               unsigned* __restrict__ flags,  // [512] ws
                               float* __restrict__ o_wrecd,
                               float* __restrict__ o_woutd,
                               float* __restrict__ o_wff) {
  int idx = blockIdx.x * blockDim.x + threadIdx.x;
  if (idx < NB_REC * NB_REC) {
    int i = idx >> 10;
    float v = d_sign[i] * fabsf(w_rec[idx]);
    f_wrecd[idx] = v;
    o_wrecd[idx] = v;
    return;
  }
  int idx2 = idx - NB_REC * NB_REC;
  if (idx2 < NB_REC * NB_OUT) {
    int i = idx2 >> 6;
    o_woutd[idx2] = d_sign[i] * fabsf(w_out[idx2]);
    return;
  }
  int idx3 = idx2 - NB_REC * NB_OUT;
  if (idx3 < NB_IN * NB_REC) {
    o_wff[idx3] = w_ff[idx3];
    return;
  }
  int idx4 = idx3 - NB_IN * NB_REC;
  if (idx4 < NB_REC) {
    f_wrecd[(size_t)NB_REC * NB_REC + idx4] = 0.0f;   // zero row 1024
    return;
  }
  int idx5 = idx4 - NB_REC;
  if (idx5 < N_FLAGS) flags[idx5] = 0u;               // replay-safe reset
}

// ---------------------------------------------------------------------------
// in_ff = inputs @ w_ff emulating np.einsum: serial c-ascending f32 chain,
// separate mul/add roundings (no FMA). VERBATIM from passing r7-r10.
// ---------------------------------------------------------------------------
__global__ __launch_bounds__(256)
void inff_einsum(const float* __restrict__ A,    // [rows,256]
                 const float* __restrict__ Bw,   // [256,1024]
                 float* __restrict__ C,          // [rows,1024]
                 int rows) {
  const int r0 = blockIdx.x * 8;
  const int d  = blockIdx.y * 256 + threadIdx.x;

  __shared__ float a_s[8][NB_IN];
  for (int e = threadIdx.x; e < 8 * NB_IN; e += 256) {
    int rr = e >> 8, cc = e & 255;
    a_s[rr][cc] = (r0 + rr < rows) ? A[(size_t)(r0 + rr) * NB_IN + cc] : 0.0f;
  }
  __syncthreads();

  float acc[8] = {0.f, 0.f, 0.f, 0.f, 0.f, 0.f, 0.f, 0.f};
  for (int c = 0; c < NB_IN; ++c) {
    const float w = Bw[(size_t)c * NB_REC + d];
#pragma unroll
    for (int rr = 0; rr < 8; ++rr)
      acc[rr] = __fadd_rn(acc[rr], __fmul_rn(a_s[rr][c], w));  // no FMA
  }
#pragma unroll
  for (int rr = 0; rr < 8; ++rr)
    if (r0 + rr < rows) C[(size_t)(r0 + rr) * NB_REC + d] = acc[rr];
}

// ---------------------------------------------------------------------------
// rnn pair-split: 256 blocks x 512 threads; block (b,h) owns columns
// [h*512,(h+1)*512). Per-step 512-bit spike-mask exchange through ws with
// agent-scope RELEASE/ACQUIRE atomics + flag handshake. Timeout -> counter.
// Compaction + zero-pad group-16 gather + state chains identical to r10.
// ---------------------------------------------------------------------------
__global__ __launch_bounds__(512, 1)
void rnn_pair(const float* __restrict__ inff,    // [128,300,1024]
              const float* __restrict__ noise,   // [128,300,1024]
              const float* __restrict__ w_rec_d, // [1025,1024] f32, ws
              float* __restrict__ spk_rec,       // [128,300,1024]
              unsigned* __restrict__ flags,      // [512] ws
              unsigned* __restrict__ gmask) {    // [2][128][2][16] u32 ws
  const int bid = blockIdx.x;
  const int b = bid & 127;
  const int h = bid >> 7;            // column half
  const int tid = threadIdx.x;       // 0..511
  const int lane = tid & 63;
  const int wv = tid >> 6;           // wave 0..7
  const int j = (h << 9) + tid;      // global column / neuron id

  __shared__ unsigned s_own[2][16];
  __shared__ uint4 sidx4_s[8][136];  // per-wave 1088 u16 entries
  unsigned short* sidxw = (unsigned short*)sidx4_s[wv];
  const uint4* sidx4w = (const uint4*)sidx4_s[wv];

  float syn = 0.0f, mem = 0.0f;
  int rst1 = 0, rst2 = 0;

  spk_rec[((size_t)b * NB_STEPS) * NB_REC + j] = 0.0f;

  const float* wc = w_rec_d + j;     // column j, row stride 1024

  float inf = inff[((size_t)b * NB_STEPS) * NB_REC + j];
  float nz  = noise[((size_t)b * NB_STEPS) * NB_REC + j];

  unsigned* myflag = &flags[bid];
  unsigned* pflag  = &flags[bid ^ 128];
  int alive = 1;                      // tid0-private

  for (int t = 0; t < TSTEPS; ++t) {
    const int p = t & 1;
    const size_t row = (size_t)b * NB_STEPS + t;

    const float mem_eff = (rst1 | rst2) ? 0.0f : mem;
    const int spike = (__fsub_rn(mem_eff, 1.0f) > 0.0f) ? 1 : 0;

    const unsigned long long msk = __ballot(spike);
    if (lane == 0) {
      const unsigned lo = (unsigned)msk, hi = (unsigned)(msk >> 32);
      unsigned* gm = &gmask[(((size_t)p * BATCH + b) * 2 + h) * 16 + 2 * wv];
      __hip_atomic_store(&gm[0], lo, __ATOMIC_RELEASE, __HIP_MEMORY_SCOPE_AGENT);
      __hip_atomic_store(&gm[1], hi, __ATOMIC_RELEASE, __HIP_MEMORY_SCOPE_AGENT);
      s_own[p][2 * wv]     = lo;
      s_own[p][2 * wv + 1] = hi;
    }

    // prefetch next step's inputs (hides HBM latency under handshake+gather)
    const float infn = inff[(row + 1) * NB_REC + j];
    const float nzn  = noise[(row + 1) * NB_REC + j];

    __syncthreads();  // (B1) own masks in LDS + global release-stores done

    if (tid == 0) {
      __hip_atomic_store(myflag, (unsigned)(t + 1), __ATOMIC_RELEASE,
                         __HIP_MEMORY_SCOPE_AGENT);
      if (alive) {
        unsigned v; int iter = 0;
        do {
          v = __hip_atomic_load(pflag, __ATOMIC_ACQUIRE,
                                __HIP_MEMORY_SCOPE_AGENT);
        } while (v < (unsigned)(t + 1) && ++iter < 500000);
        if (v < (unsigned)(t + 1)) {
          alive = 0;                                  // stop waiting forever
          atomicAdd(&flags[256], 1u);                 // diagnostic counter
        }
      }
    }
    __syncthreads();  // (B2) partner masks visible (HB via acquire + barrier)

    // full 32-word view: own half from LDS, partner half via acquire loads
    unsigned m0 = 0;
    if (lane < 32) {
      const int hw = lane >> 4, widx = lane & 15;
      if (hw == h) {
        m0 = s_own[p][widx];
      } else {
        m0 = __hip_atomic_load(
            &gmask[(((size_t)p * BATCH + b) * 2 + (1 ^ h)) * 16 + widx],
            __ATOMIC_ACQUIRE, __HIP_MEMORY_SCOPE_AGENT);
      }
    }

    // per-wave ascending compaction (identical to r10)
    const int pc = __popc(m0);
    int x = pc;
#pragma unroll
    for (int d = 1; d < 64; d <<= 1) {
      int y = __shfl_up(x, (unsigned)d, 64);
      if (lane >= d) x += y;
    }
    int base = x - pc;
    unsigned m = m0;
    while (m) {
      const int bit = __builtin_ctz(m);
      m &= m - 1;
      sidxw[base++] = (unsigned short)((lane << 5) + bit);
    }
    const int S = __shfl(x, 63);
    if (lane < 48) sidxw[S + lane] = (unsigned short)NB_REC;  // pad -> zero row

    // group-16 double-buffered gather; strictly serial ascending f32 chain
    auto load16 = [&](int k, float* buf) {
      const uint4 p0 = sidx4w[(k >> 3) + 0];
      const uint4 p1 = sidx4w[(k >> 3) + 1];
      const unsigned e[16] = {
          p0.x & 0xffffu, p0.x >> 16, p0.y & 0xffffu, p0.y >> 16,
          p0.z & 0xffffu, p0.z >> 16, p0.w & 0xffffu, p0.w >> 16,
          p1.x & 0xffffu, p1.x >> 16, p1.y & 0xffffu, p1.y >> 16,
          p1.z & 0xffffu, p1.z >> 16, p1.w & 0xffffu, p1.w >> 16};
#pragma unroll
      for (int q = 0; q < 16; ++q)
        buf[q] = wc[(size_t)e[q] << 10];
    };

    float acc = 0.0f;
    float bufA[16], bufB[16];
    load16(0, bufA);
    for (int k0 = 0; k0 < S; k0 += 32) {
      load16(k0 + 16, bufB);
#pragma unroll
      for (int q = 0; q < 16; ++q) acc = __fadd_rn(acc, bufA[q]);
      load16(k0 + 32, bufA);
#pragma unroll
      for (int q = 0; q < 16; ++q) acc = __fadd_rn(acc, bufB[q]);
    }

    const float new_syn =
        __fadd_rn(__fadd_rn(__fadd_rn(__fmul_rn(ALPHA_F, syn), acc), inf), nz);
    const float new_mem =
        __fsub_rn(__fadd_rn(__fmul_rn(BETA_F, mem_eff), syn), (float)spike);

    spk_rec[(row + 1) * NB_REC + j] = (float)spike;

    syn = new_syn;
    mem = new_mem;
    rst2 = rst1;
    rst1 = spike;
    inf = infn;
    nz = nzn;
  }
}

// ---------------------------------------------------------------------------
// out_rec[r,:] = spk_rec[r,:] @ w_out_d for ALL 38400 rows (row t=0 -> 0).
// Same ascending serial f32 chain as passing r8-r10. Reads d_out wout copy
// (bit-identical to the ws copy r10 used).
// ---------------------------------------------------------------------------
__global__ __launch_bounds__(256)
void h2_kernel(const float* __restrict__ spk_rec,  // [38400,1024]
               const float* __restrict__ w_out_d,  // [1024,64]
               float* __restrict__ out_rec,        // [38400,64]
               int nrows) {
  const int r = blockIdx.x * 4 + (threadIdx.x >> 6);
  const int lane = threadIdx.x & 63;
  if (r >= nrows) return;

  const float* spk = spk_rec + (size_t)r * NB_REC;
  const float* wo  = w_out_d + lane;

  unsigned long long mw[16];
#pragma unroll
  for (int c = 0; c < 16; ++c)
    mw[c] = __ballot(spk[c * 64 + lane] != 0.0f);

  float acc = 0.0f;
#pragma unroll
  for (int c = 0; c < 16; ++c) {
    unsigned long long m = mw[c];
    while (m) {                     // uniform across the wave
      float w[8];
#pragma unroll
      for (int q = 0; q < 8; ++q) {
        const bool v = (m != 0ull);
        const int idx = v ? __builtin_ctzll(m) : 0;
        m &= m - 1ull;
        const float ld = wo[(size_t)(v ? (c * 64 + idx) : 0) << 6];
        w[q] = v ? ld : 0.0f;
      }
#pragma unroll
      for (int q = 0; q < 8; ++q) acc = __fadd_rn(acc, w[q]);
    }
  }
  out_rec[(size_t)r * NB_OUT + lane] = acc;
}

// ---------------------------------------------------------------------------
extern "C" void kernel_launch(void* const* d_in, const int* in_sizes, int n_in,
                              void* d_out, int out_size, void* d_ws, size_t ws_size,
                              hipStream_t stream) {
  const float *inputs = nullptr, *noise = nullptr, *w_ff = nullptr,
              *w_rec = nullptr, *w_out = nullptr, *d_sign = nullptr;
  for (int i = 0; i < n_in; ++i) {
    switch (in_sizes[i]) {
      case SZ_INPUTS: inputs = (const float*)d_in[i]; break;
      case SZ_NOISE:  noise  = (const float*)d_in[i]; break;
      case SZ_WFF:    w_ff   = (const float*)d_in[i]; break;
      case SZ_WREC:   w_rec  = (const float*)d_in[i]; break;
      case SZ_WOUT:   w_out  = (const float*)d_in[i]; break;
      case SZ_DSIGN:  d_sign = (const float*)d_in[i]; break;
      default: break;
    }
  }

  float* out = (float*)d_out;

  // ws layout: [f_wrecd 1025x1024][flags 512 u32][gmask 8192 u32][inff]
  const size_t WREC_ELEMS = (size_t)WREC_ROWS * NB_REC;
  const size_t need = (WREC_ELEMS + N_FLAGS + N_MASKW) * sizeof(float) +
                      (size_t)BATCH * NB_STEPS * NB_REC * sizeof(float);

  float sentinel = 0.0f;
  if (!inputs || !noise || !w_ff || !w_rec || !w_out || !d_sign) {
    sentinel = 300.0f;
  } else if (out_size != OUT_TOTAL) {
    sentinel = 700.0f;
  } else if (need > ws_size) {
    sentinel = 500.0f + (float)(ws_size >> 20);
  }

  if (sentinel != 0.0f) {
    sentinel_kernel<<<1, 1, 0, stream>>>(out, sentinel);
    return;
  }

  float* out_rec = out + OUT_REC_OFF;
  float* spk_rec = out + SPK_REC_OFF;
  float* o_wrecd = out + WRECD_OFF;
  float* o_woutd = out + WOUTD_OFF;
  float* o_wff   = out + WFF_OFF;

  float* f_wrecd   = (float*)d_ws;
  unsigned* flags  = (unsigned*)(f_wrecd + WREC_ELEMS);
  unsigned* gmask  = flags + N_FLAGS;
  float* inff      = (float*)(gmask + N_MASKW);

  {
    int total = NB_REC * NB_REC + NB_REC * NB_OUT + NB_IN * NB_REC +
                NB_REC + N_FLAGS;
    int blocks = (total + 255) / 256;
    weights_kernel<<<blocks, 256, 0, stream>>>(w_rec, w_out, w_ff, d_sign,
                                               f_wrecd, flags,
                                               o_wrecd, o_woutd, o_wff);
  }

  {
    const int rows = BATCH * NB_STEPS;  // 38400
    dim3 ggrid((rows + 7) / 8, NB_REC / 256);
    inff_einsum<<<ggrid, 256, 0, stream>>>(inputs, w_ff, inff, rows);
  }

  rnn_pair<<<2 * BATCH, 512, 0, stream>>>(inff, noise, f_wrecd, spk_rec,
                                          flags, gmask);

  {
    const int nrows = BATCH * NB_STEPS;  // 38400
    h2_kernel<<<(nrows + 3) / 4, 256, 0, stream>>>(spk_rec, o_woutd,
                                                   out_rec, nrows);
  }

  check_kernel<<<1, 1, 0, stream>>>(&flags[256], out);
}

// Round 13
// 2214.192 us; speedup vs baseline: 9.5208x; 9.5208x over previous
//
#include <hip/hip_runtime.h>

// ---------------------------------------------------------------------------
// SpikeRNN — r13: r10 structure restored (pair-split retired: r12 proved the
// cross-CU handshake costs 68us/step). Numerics bit-identical to r7-r12.
//  * rnn gather: pre-scaled u32 byte offsets in LDS + SADDR-form loads
//    (1 v_add per load instead of u16 unpack + 64-bit addr chain).
//  * rnn publishes per-step 1024-bit spike masks (16 u64) to ws; h2_fast
//    reads masks (128B/row) instead of spk_rec floats (4KB/row). Fallback
//    to r8's proven spk-reading h2 if ws can't hold the mask buffer.
//  * einsum / weights verbatim from passing rounds.
// ---------------------------------------------------------------------------

constexpr int NB_IN  = 256;
constexpr int NB_REC = 1024;
constexpr int NB_OUT = 64;
constexpr int BATCH  = 128;
constexpr int NB_STEPS = 300;
constexpr int TSTEPS = NB_STEPS - 1;

constexpr float ALPHA_F = (float)0.8187307530779818;  // f32(exp(-0.2))
constexpr float BETA_F  = (float)0.9048374180359595;  // f32(exp(-0.1))

// d_out element offsets (f32 elements)
constexpr size_t OUT_REC_OFF = 0;
constexpr size_t SPK_REC_OFF = (size_t)BATCH * NB_STEPS * NB_OUT;
constexpr size_t WRECD_OFF   = SPK_REC_OFF + (size_t)BATCH * NB_STEPS * NB_REC;
constexpr size_t WOUTD_OFF   = WRECD_OFF + (size_t)NB_REC * NB_REC;
constexpr size_t WFF_OFF     = WOUTD_OFF + (size_t)NB_REC * NB_OUT;
constexpr int    OUT_TOTAL   = 43155456;

constexpr int SZ_INPUTS = BATCH * NB_STEPS * NB_IN;   // 9,830,400
constexpr int SZ_NOISE  = BATCH * NB_STEPS * NB_REC;  // 39,321,600
constexpr int SZ_WFF    = NB_IN * NB_REC;             // 262,144
constexpr int SZ_WREC   = NB_REC * NB_REC;            // 1,048,576
constexpr int SZ_WOUT   = NB_REC * NB_OUT;            // 65,536
constexpr int SZ_DSIGN  = NB_REC;                     // 1,024

constexpr int WREC_ROWS = NB_REC + 1;                 // +1 zero row (pad idx)
constexpr int NROWS     = BATCH * NB_STEPS;           // 38400

__global__ void sentinel_kernel(float* out, float v) { out[0] = v; }

// ---------------------------------------------------------------------------
// Dale weights -> ws f32 [1025,1024] (+zero row) and d_out copies.
// ---------------------------------------------------------------------------
__global__ void weights_kernel(const float* __restrict__ w_rec,
                               const float* __restrict__ w_out,
                               const float* __restrict__ w_ff,
                               const float* __restrict__ d_sign,
                               float* __restrict__ f_wrecd,   // [1025,1024] ws
                               float* __restrict__ o_wrecd,
                               float* __restrict__ o_woutd,
                               float* __restrict__ o_wff) {
  int idx = blockIdx.x * blockDim.x + threadIdx.x;
  if (idx < NB_REC * NB_REC) {
    int i = idx >> 10;
    float v = d_sign[i] * fabsf(w_rec[idx]);
    f_wrecd[idx] = v;
    o_wrecd[idx] = v;
    return;
  }
  int idx2 = idx - NB_REC * NB_REC;
  if (idx2 < NB_REC * NB_OUT) {
    int i = idx2 >> 6;
    o_woutd[idx2] = d_sign[i] * fabsf(w_out[idx2]);
    return;
  }
  int idx3 = idx2 - NB_REC * NB_OUT;
  if (idx3 < NB_IN * NB_REC) {
    o_wff[idx3] = w_ff[idx3];
    return;
  }
  int idx4 = idx3 - NB_IN * NB_REC;
  if (idx4 < NB_REC) {
    f_wrecd[(size_t)NB_REC * NB_REC + idx4] = 0.0f;   // zero row 1024
  }
}

// ---------------------------------------------------------------------------
// in_ff = inputs @ w_ff emulating np.einsum: serial c-ascending f32 chain,
// separate mul/add roundings (no FMA). VERBATIM from passing r7-r12.
// ---------------------------------------------------------------------------
__global__ __launch_bounds__(256)
void inff_einsum(const float* __restrict__ A,    // [rows,256]
                 const float* __restrict__ Bw,   // [256,1024]
                 float* __restrict__ C,          // [rows,1024]
                 int rows) {
  const int r0 = blockIdx.x * 8;
  const int d  = blockIdx.y * 256 + threadIdx.x;

  __shared__ float a_s[8][NB_IN];
  for (int e = threadIdx.x; e < 8 * NB_IN; e += 256) {
    int rr = e >> 8, cc = e & 255;
    a_s[rr][cc] = (r0 + rr < rows) ? A[(size_t)(r0 + rr) * NB_IN + cc] : 0.0f;
  }
  __syncthreads();

  float acc[8] = {0.f, 0.f, 0.f, 0.f, 0.f, 0.f, 0.f, 0.f};
  for (int c = 0; c < NB_IN; ++c) {
    const float w = Bw[(size_t)c * NB_REC + d];
#pragma unroll
    for (int rr = 0; rr < 8; ++rr)
      acc[rr] = __fadd_rn(acc[rr], __fmul_rn(a_s[rr][c], w));  // no FMA
  }
#pragma unroll
  for (int rr = 0; rr < 8; ++rr)
    if (r0 + rr < rows) C[(size_t)(r0 + rr) * NB_REC + d] = acc[rr];
}

// ---------------------------------------------------------------------------
// 299-step recurrence. 1024 threads (16 waves), thread j = neuron/column j.
// r10 structure: ping-pong masks, ONE barrier/step, per-wave private
// ascending compaction, zero-row padding, group-16 double-buffered gather.
// r13: LDS holds PRE-SCALED u32 byte offsets (row<<12); loads are
// base-SGPR + 32-bit voffset (one v_add per load). Optional mask publish
// (gws != nullptr) for the fast h2 path. Chains bit-identical to r10.
// ---------------------------------------------------------------------------
__global__ __launch_bounds__(1024, 1)
void rnn_kernel(const float* __restrict__ inff,    // [128,300,1024]
                const float* __restrict__ noise,   // [128,300,1024]
                const float* __restrict__ w_rec_d, // [1025,1024] f32, ws
                float* __restrict__ spk_rec,       // [128,300,1024]
                unsigned long long* __restrict__ gws) {  // [38400][16] or null
  const int b = blockIdx.x;
  const int j = threadIdx.x;
  const int lane = j & 63;
  const int wv = j >> 6;       // wave 0..15

  __shared__ unsigned s_mask[2][32];
  __shared__ uint4 soff4[16][272];   // per-wave 1088 u32 byte offsets

  unsigned* soffw = (unsigned*)soff4[wv];
  const uint4* soff4w = soff4[wv];

  float syn = 0.0f, mem = 0.0f;
  int rst1 = 0, rst2 = 0;

  spk_rec[((size_t)b * NB_STEPS) * NB_REC + j] = 0.0f;

  const char* wbase = (const char*)w_rec_d;
  const unsigned jb = (unsigned)(j << 2);

  // prefetch t=0 inputs
  float inf = inff[((size_t)b * NB_STEPS) * NB_REC + j];
  float nz  = noise[((size_t)b * NB_STEPS) * NB_REC + j];

  for (int t = 0; t < TSTEPS; ++t) {
    const int p = t & 1;
    const size_t row = (size_t)b * NB_STEPS + t;

    const float mem_eff = (rst1 | rst2) ? 0.0f : mem;
    const int spike = (__fsub_rn(mem_eff, 1.0f) > 0.0f) ? 1 : 0;

    const unsigned long long msk = __ballot(spike);
    if (lane == 0) {
      s_mask[p][2 * wv]     = (unsigned)msk;
      s_mask[p][2 * wv + 1] = (unsigned)(msk >> 32);
      if (gws) gws[(row + 1) * 16 + wv] = msk;   // publish for h2_fast
    }

    // independent stores/loads issued before the barrier
    spk_rec[(row + 1) * NB_REC + j] = (float)spike;
    const float infn = inff[(row + 1) * NB_REC + j];
    const float nzn  = noise[(row + 1) * NB_REC + j];

    __syncthreads();  // (B) masks complete; prev-iter offset reads long done

    // per-wave private ascending compaction -> pre-scaled byte offsets
    const unsigned m0 = (lane < 32) ? s_mask[p][lane] : 0u;
    const int pc = __popc(m0);
    int x = pc;
#pragma unroll
    for (int d = 1; d < 64; d <<= 1) {
      int y = __shfl_up(x, (unsigned)d, 64);
      if (lane >= d) x += y;
    }
    int base = x - pc;           // exclusive prefix
    unsigned m = m0;
    while (m) {
      const int bit = __builtin_ctz(m);
      m &= m - 1;
      soffw[base++] = (unsigned)(((lane << 5) + bit) << 12);
    }
    const int S = __shfl(x, 63); // total spike count
    if (lane < 48) soffw[S + lane] = (unsigned)(NB_REC << 12);  // pad -> zero row

    // group-16 double-buffered gather; strictly serial ascending f32 chain
    auto load16 = [&](int k, float* buf) {
      const uint4 o0 = soff4w[(k >> 2) + 0];
      const uint4 o1 = soff4w[(k >> 2) + 1];
      const uint4 o2 = soff4w[(k >> 2) + 2];
      const uint4 o3 = soff4w[(k >> 2) + 3];
      const unsigned e[16] = {o0.x, o0.y, o0.z, o0.w, o1.x, o1.y, o1.z, o1.w,
                              o2.x, o2.y, o2.z, o2.w, o3.x, o3.y, o3.z, o3.w};
#pragma unroll
      for (int q = 0; q < 16; ++q)
        buf[q] = *reinterpret_cast<const float*>(wbase + (size_t)(e[q] + jb));
    };

    float acc = 0.0f;
    float bufA[16], bufB[16];
    load16(0, bufA);
    for (int k0 = 0; k0 < S; k0 += 32) {
      load16(k0 + 16, bufB);
#pragma unroll
      for (int q = 0; q < 16; ++q) acc = __fadd_rn(acc, bufA[q]);
      load16(k0 + 32, bufA);
#pragma unroll
      for (int q = 0; q < 16; ++q) acc = __fadd_rn(acc, bufB[q]);
    }

    // reference order, separate roundings, no FMA
    const float new_syn =
        __fadd_rn(__fadd_rn(__fadd_rn(__fmul_rn(ALPHA_F, syn), acc), inf), nz);
    const float new_mem =
        __fsub_rn(__fadd_rn(__fmul_rn(BETA_F, mem_eff), syn), (float)spike);

    syn = new_syn;
    mem = new_mem;
    rst2 = rst1;
    rst1 = spike;
    inf = infn;
    nz = nzn;
  }
}

// ---------------------------------------------------------------------------
// h2_fast: out_rec[r,:] from the published mask words (128B/row) — no spk
// re-read. Rows r%300==0 -> zeros. Chain identical to proven r8 h2.
// ---------------------------------------------------------------------------
__global__ __launch_bounds__(256)
void h2_fast(const unsigned long long* __restrict__ gws,  // [38400][16]
             const float* __restrict__ w_out_d,           // [1024,64]
             float* __restrict__ out_rec,                 // [38400,64]
             int nrows) {
  const int r = blockIdx.x * 4 + (threadIdx.x >> 6);
  const int lane = threadIdx.x & 63;
  if (r >= nrows) return;
  if (r % NB_STEPS == 0) {               // t = 0 rows are all-zero
    out_rec[(size_t)r * NB_OUT + lane] = 0.0f;
    return;
  }

  const unsigned long long* mrow = gws + (size_t)r * 16;
  unsigned long long mw[16];
#pragma unroll
  for (int c = 0; c < 16; ++c) mw[c] = mrow[c];   // wave-uniform loads

  const float* wo = w_out_d + lane;

  float acc = 0.0f;
#pragma unroll
  for (int c = 0; c < 16; ++c) {
    unsigned long long m = mw[c];
    while (m) {                     // uniform across the wave
      float w[8];
#pragma unroll
      for (int q = 0; q < 8; ++q) {
        const bool v = (m != 0ull);
        const int idx = v ? __builtin_ctzll(m) : 0;
        m &= m - 1ull;
        const float ld = wo[(size_t)(v ? (c * 64 + idx) : 0) << 6];
        w[q] = v ? ld : 0.0f;
      }
#pragma unroll
      for (int q = 0; q < 8; ++q) acc = __fadd_rn(acc, w[q]);
    }
  }
  out_rec[(size_t)r * NB_OUT + lane] = acc;
}

// ---------------------------------------------------------------------------
// h2_slow: VERBATIM r8 fallback (reads spk_rec floats + ballots).
// ---------------------------------------------------------------------------
__global__ __launch_bounds__(256)
void h2_slow(const float* __restrict__ spk_rec,  // [38400,1024]
             const float* __restrict__ w_out_d,  // [1024,64]
             float* __restrict__ out_rec,        // [38400,64]
             int nrows) {
  const int r = blockIdx.x * 4 + (threadIdx.x >> 6);
  const int lane = threadIdx.x & 63;
  if (r >= nrows) return;

  const float* spk = spk_rec + (size_t)r * NB_REC;
  const float* wo  = w_out_d + lane;

  unsigned long long mw[16];
#pragma unroll
  for (int c = 0; c < 16; ++c)
    mw[c] = __ballot(spk[c * 64 + lane] != 0.0f);

  float acc = 0.0f;
#pragma unroll
  for (int c = 0; c < 16; ++c) {
    unsigned long long m = mw[c];
    while (m) {
      float w[8];
#pragma unroll
      for (int q = 0; q < 8; ++q) {
        const bool v = (m != 0ull);
        const int idx = v ? __builtin_ctzll(m) : 0;
        m &= m - 1ull;
        const float ld = wo[(size_t)(v ? (c * 64 + idx) : 0) << 6];
        w[q] = v ? ld : 0.0f;
      }
#pragma unroll
      for (int q = 0; q < 8; ++q) acc = __fadd_rn(acc, w[q]);
    }
  }
  out_rec[(size_t)r * NB_OUT + lane] = acc;
}

// ---------------------------------------------------------------------------
extern "C" void kernel_launch(void* const* d_in, const int* in_sizes, int n_in,
                              void* d_out, int out_size, void* d_ws, size_t ws_size,
                              hipStream_t stream) {
  const float *inputs = nullptr, *noise = nullptr, *w_ff = nullptr,
              *w_rec = nullptr, *w_out = nullptr, *d_sign = nullptr;
  for (int i = 0; i < n_in; ++i) {
    switch (in_sizes[i]) {
      case SZ_INPUTS: inputs = (const float*)d_in[i]; break;
      case SZ_NOISE:  noise  = (const float*)d_in[i]; break;
      case SZ_WFF:    w_ff   = (const float*)d_in[i]; break;
      case SZ_WREC:   w_rec  = (const float*)d_in[i]; break;
      case SZ_WOUT:   w_out  = (const float*)d_in[i]; break;
      case SZ_DSIGN:  d_sign = (const float*)d_in[i]; break;
      default: break;
    }
  }

  float* out = (float*)d_out;

  const size_t WREC_ELEMS = (size_t)WREC_ROWS * NB_REC;
  const size_t WREC_BYTES = WREC_ELEMS * sizeof(float);          // 4.2 MB
  const size_t GWS_BYTES  = (size_t)NROWS * 16 * 8;              // 4.9 MB
  const size_t INFF_BYTES = (size_t)NROWS * NB_REC * sizeof(float); // 157 MB

  const size_t need_fast = WREC_BYTES + GWS_BYTES + INFF_BYTES;
  const size_t need_slow = WREC_BYTES + INFF_BYTES;

  float sentinel = 0.0f;
  if (!inputs || !noise || !w_ff || !w_rec || !w_out || !d_sign) {
    sentinel = 300.0f;
  } else if (out_size != OUT_TOTAL) {
    sentinel = 700.0f;
  } else if (need_slow > ws_size) {
    sentinel = 500.0f + (float)(ws_size >> 20);
  }

  if (sentinel != 0.0f) {
    sentinel_kernel<<<1, 1, 0, stream>>>(out, sentinel);
    return;
  }

  const bool fast = (need_fast <= ws_size);

  float* out_rec = out + OUT_REC_OFF;
  float* spk_rec = out + SPK_REC_OFF;
  float* o_wrecd = out + WRECD_OFF;
  float* o_woutd = out + WOUTD_OFF;
  float* o_wff   = out + WFF_OFF;

  float* f_wrecd = (float*)d_ws;
  unsigned long long* gws =
      fast ? (unsigned long long*)(f_wrecd + WREC_ELEMS) : nullptr;
  float* inff = fast ? (float*)(gws + (size_t)NROWS * 16)
                     : (f_wrecd + WREC_ELEMS);

  {
    int total = NB_REC * NB_REC + NB_REC * NB_OUT + NB_IN * NB_REC + NB_REC;
    int blocks = (total + 255) / 256;
    weights_kernel<<<blocks, 256, 0, stream>>>(w_rec, w_out, w_ff, d_sign,
                                               f_wrecd,
                                               o_wrecd, o_woutd, o_wff);
  }

  {
    dim3 ggrid((NROWS + 7) / 8, NB_REC / 256);
    inff_einsum<<<ggrid, 256, 0, stream>>>(inputs, w_ff, inff, NROWS);
  }

  rnn_kernel<<<BATCH, 1024, 0, stream>>>(inff, noise, f_wrecd, spk_rec, gws);

  if (fast) {
    h2_fast<<<(NROWS + 3) / 4, 256, 0, stream>>>(gws, o_woutd, out_rec, NROWS);
  } else {
    h2_slow<<<(NROWS + 3) / 4, 256, 0, stream>>>(spk_rec, o_woutd,
                                                 out_rec, NROWS);
  }
}

// Round 15
// 2060.926 us; speedup vs baseline: 10.2288x; 1.0744x over previous
//
#include <hip/hip_runtime.h>

// ---------------------------------------------------------------------------
// SpikeRNN — r15: r13 (passing, 2214us) with ONE safe change: einsum does
// 16 rows x 2 cols/thread with a transposed, padded LDS A-tile (float4 reads,
// 16B-aligned rows). Arithmetic chain per output is instruction-identical to
// the proven scalar version (ascending c, __fadd_rn/__fmul_rn, no FMA).
// Packed-FP32 (v_pk_*) is BANNED: r11+r14 proved it is not bit-identical to
// the scalar VALU path on gfx950. rnn / h2 / weights verbatim from r13.
// ---------------------------------------------------------------------------

constexpr int NB_IN  = 256;
constexpr int NB_REC = 1024;
constexpr int NB_OUT = 64;
constexpr int BATCH  = 128;
constexpr int NB_STEPS = 300;
constexpr int TSTEPS = NB_STEPS - 1;

constexpr float ALPHA_F = (float)0.8187307530779818;  // f32(exp(-0.2))
constexpr float BETA_F  = (float)0.9048374180359595;  // f32(exp(-0.1))

// d_out element offsets (f32 elements)
constexpr size_t OUT_REC_OFF = 0;
constexpr size_t SPK_REC_OFF = (size_t)BATCH * NB_STEPS * NB_OUT;
constexpr size_t WRECD_OFF   = SPK_REC_OFF + (size_t)BATCH * NB_STEPS * NB_REC;
constexpr size_t WOUTD_OFF   = WRECD_OFF + (size_t)NB_REC * NB_REC;
constexpr size_t WFF_OFF     = WOUTD_OFF + (size_t)NB_REC * NB_OUT;
constexpr int    OUT_TOTAL   = 43155456;

constexpr int SZ_INPUTS = BATCH * NB_STEPS * NB_IN;   // 9,830,400
constexpr int SZ_NOISE  = BATCH * NB_STEPS * NB_REC;  // 39,321,600
constexpr int SZ_WFF    = NB_IN * NB_REC;             // 262,144
constexpr int SZ_WREC   = NB_REC * NB_REC;            // 1,048,576
constexpr int SZ_WOUT   = NB_REC * NB_OUT;            // 65,536
constexpr int SZ_DSIGN  = NB_REC;                     // 1,024

constexpr int WREC_ROWS = NB_REC + 1;                 // +1 zero row (pad idx)
constexpr int NROWS     = BATCH * NB_STEPS;           // 38400

__global__ void sentinel_kernel(float* out, float v) { out[0] = v; }

// ---------------------------------------------------------------------------
// Dale weights -> ws f32 [1025,1024] (+zero row) and d_out copies. (r13)
// ---------------------------------------------------------------------------
__global__ void weights_kernel(const float* __restrict__ w_rec,
                               const float* __restrict__ w_out,
                               const float* __restrict__ w_ff,
                               const float* __restrict__ d_sign,
                               float* __restrict__ f_wrecd,   // [1025,1024] ws
                               float* __restrict__ o_wrecd,
                               float* __restrict__ o_woutd,
                               float* __restrict__ o_wff) {
  int idx = blockIdx.x * blockDim.x + threadIdx.x;
  if (idx < NB_REC * NB_REC) {
    int i = idx >> 10;
    float v = d_sign[i] * fabsf(w_rec[idx]);
    f_wrecd[idx] = v;
    o_wrecd[idx] = v;
    return;
  }
  int idx2 = idx - NB_REC * NB_REC;
  if (idx2 < NB_REC * NB_OUT) {
    int i = idx2 >> 6;
    o_woutd[idx2] = d_sign[i] * fabsf(w_out[idx2]);
    return;
  }
  int idx3 = idx2 - NB_REC * NB_OUT;
  if (idx3 < NB_IN * NB_REC) {
    o_wff[idx3] = w_ff[idx3];
    return;
  }
  int idx4 = idx3 - NB_IN * NB_REC;
  if (idx4 < NB_REC) {
    f_wrecd[(size_t)NB_REC * NB_REC + idx4] = 0.0f;   // zero row 1024
  }
}

// ---------------------------------------------------------------------------
// einsum16: in_ff = inputs @ w_ff. 16 rows x 2 cols per thread-block-column.
// LDS A-tile transposed [c][rr] with pad 20 (80B rows -> 16B-aligned float4).
// Per output: ascending-c chain of __fadd_rn(acc, __fmul_rn(a,w)) — identical
// instruction sequence to the proven r7-r13 einsum. No packed ops, no FMA.
// grid (2400, 2), block 256. 38400 % 16 == 0 -> no tails.
// ---------------------------------------------------------------------------
__global__ __launch_bounds__(256)
void inff_einsum16(const float* __restrict__ A,    // [38400,256]
                   const float* __restrict__ Bw,   // [256,1024]
                   float* __restrict__ C) {        // [38400,1024]
  const int r0 = blockIdx.x * 16;
  const int tid = threadIdx.x;
  const int d = blockIdx.y * 512 + 2 * tid;        // column pair

  __shared__ float a_s[NB_IN][20];   // [c][rr], rows 80B (16B-aligned)

#pragma unroll
  for (int k = 0; k < 16; ++k) {
    // iteration k: all threads load row r0+k, col tid (coalesced 1KB)
    a_s[tid][k] = A[(size_t)(r0 + k) * NB_IN + tid];
  }
  __syncthreads();

  float accL[16], accR[16];
#pragma unroll
  for (int rr = 0; rr < 16; ++rr) { accL[rr] = 0.0f; accR[rr] = 0.0f; }

  const float* bw = Bw + d;
  for (int c = 0; c < NB_IN; ++c) {
    const float2 w2 = *reinterpret_cast<const float2*>(bw + (size_t)c * NB_REC);
    const float4 qa = *reinterpret_cast<const float4*>(&a_s[c][0]);
    const float4 qb = *reinterpret_cast<const float4*>(&a_s[c][4]);
    const float4 qc = *reinterpret_cast<const float4*>(&a_s[c][8]);
    const float4 qd = *reinterpret_cast<const float4*>(&a_s[c][12]);
    const float av[16] = {qa.x, qa.y, qa.z, qa.w, qb.x, qb.y, qb.z, qb.w,
                          qc.x, qc.y, qc.z, qc.w, qd.x, qd.y, qd.z, qd.w};
#pragma unroll
    for (int rr = 0; rr < 16; ++rr) {
      accL[rr] = __fadd_rn(accL[rr], __fmul_rn(av[rr], w2.x));
      accR[rr] = __fadd_rn(accR[rr], __fmul_rn(av[rr], w2.y));
    }
  }

#pragma unroll
  for (int rr = 0; rr < 16; ++rr) {
    float2 o; o.x = accL[rr]; o.y = accR[rr];
    *reinterpret_cast<float2*>(C + (size_t)(r0 + rr) * NB_REC + d) = o;
  }
}

// ---------------------------------------------------------------------------
// 299-step recurrence — VERBATIM r13 (passing, 5.7us/step, ~80% of the
// per-CU L1/L2-return bound for this structure).
// ---------------------------------------------------------------------------
__global__ __launch_bounds__(1024, 1)
void rnn_kernel(const float* __restrict__ inff,    // [128,300,1024]
                const float* __restrict__ noise,   // [128,300,1024]
                const float* __restrict__ w_rec_d, // [1025,1024] f32, ws
                float* __restrict__ spk_rec,       // [128,300,1024]
                unsigned long long* __restrict__ gws) {  // [38400][16] or null
  const int b = blockIdx.x;
  const int j = threadIdx.x;
  const int lane = j & 63;
  const int wv = j >> 6;       // wave 0..15

  __shared__ unsigned s_mask[2][32];
  __shared__ uint4 soff4[16][272];   // per-wave 1088 u32 byte offsets

  unsigned* soffw = (unsigned*)soff4[wv];
  const uint4* soff4w = soff4[wv];

  float syn = 0.0f, mem = 0.0f;
  int rst1 = 0, rst2 = 0;

  spk_rec[((size_t)b * NB_STEPS) * NB_REC + j] = 0.0f;

  const char* wbase = (const char*)w_rec_d;
  const unsigned jb = (unsigned)(j << 2);

  float inf = inff[((size_t)b * NB_STEPS) * NB_REC + j];
  float nz  = noise[((size_t)b * NB_STEPS) * NB_REC + j];

  for (int t = 0; t < TSTEPS; ++t) {
    const int p = t & 1;
    const size_t row = (size_t)b * NB_STEPS + t;

    const float mem_eff = (rst1 | rst2) ? 0.0f : mem;
    const int spike = (__fsub_rn(mem_eff, 1.0f) > 0.0f) ? 1 : 0;

    const unsigned long long msk = __ballot(spike);
    if (lane == 0) {
      s_mask[p][2 * wv]     = (unsigned)msk;
      s_mask[p][2 * wv + 1] = (unsigned)(msk >> 32);
      if (gws) gws[(row + 1) * 16 + wv] = msk;   // publish for h2_fast
    }

    spk_rec[(row + 1) * NB_REC + j] = (float)spike;
    const float infn = inff[(row + 1) * NB_REC + j];
    const float nzn  = noise[(row + 1) * NB_REC + j];

    __syncthreads();  // (B) masks complete; prev-iter offset reads long done

    const unsigned m0 = (lane < 32) ? s_mask[p][lane] : 0u;
    const int pc = __popc(m0);
    int x = pc;
#pragma unroll
    for (int d = 1; d < 64; d <<= 1) {
      int y = __shfl_up(x, (unsigned)d, 64);
      if (lane >= d) x += y;
    }
    int base = x - pc;           // exclusive prefix
    unsigned m = m0;
    while (m) {
      const int bit = __builtin_ctz(m);
      m &= m - 1;
      soffw[base++] = (unsigned)(((lane << 5) + bit) << 12);
    }
    const int S = __shfl(x, 63);
    if (lane < 48) soffw[S + lane] = (unsigned)(NB_REC << 12);  // pad -> zero row

    auto load16 = [&](int k, float* buf) {
      const uint4 o0 = soff4w[(k >> 2) + 0];
      const uint4 o1 = soff4w[(k >> 2) + 1];
      const uint4 o2 = soff4w[(k >> 2) + 2];
      const uint4 o3 = soff4w[(k >> 2) + 3];
      const unsigned e[16] = {o0.x, o0.y, o0.z, o0.w, o1.x, o1.y, o1.z, o1.w,
                              o2.x, o2.y, o2.z, o2.w, o3.x, o3.y, o3.z, o3.w};
#pragma unroll
      for (int q = 0; q < 16; ++q)
        buf[q] = *reinterpret_cast<const float*>(wbase + (size_t)(e[q] + jb));
    };

    float acc = 0.0f;
    float bufA[16], bufB[16];
    load16(0, bufA);
    for (int k0 = 0; k0 < S; k0 += 32) {
      load16(k0 + 16, bufB);
#pragma unroll
      for (int q = 0; q < 16; ++q) acc = __fadd_rn(acc, bufA[q]);
      load16(k0 + 32, bufA);
#pragma unroll
      for (int q = 0; q < 16; ++q) acc = __fadd_rn(acc, bufB[q]);
    }

    const float new_syn =
        __fadd_rn(__fadd_rn(__fadd_rn(__fmul_rn(ALPHA_F, syn), acc), inf), nz);
    const float new_mem =
        __fsub_rn(__fadd_rn(__fmul_rn(BETA_F, mem_eff), syn), (float)spike);

    syn = new_syn;
    mem = new_mem;
    rst2 = rst1;
    rst1 = spike;
    inf = infn;
    nz = nzn;
  }
}

// ---------------------------------------------------------------------------
// h2_fast / h2_slow — VERBATIM r13.
// ---------------------------------------------------------------------------
__global__ __launch_bounds__(256)
void h2_fast(const unsigned long long* __restrict__ gws,  // [38400][16]
             const float* __restrict__ w_out_d,           // [1024,64]
             float* __restrict__ out_rec,                 // [38400,64]
             int nrows) {
  const int r = blockIdx.x * 4 + (threadIdx.x >> 6);
  const int lane = threadIdx.x & 63;
  if (r >= nrows) return;
  if (r % NB_STEPS == 0) {
    out_rec[(size_t)r * NB_OUT + lane] = 0.0f;
    return;
  }

  const unsigned long long* mrow = gws + (size_t)r * 16;
  unsigned long long mw[16];
#pragma unroll
  for (int c = 0; c < 16; ++c) mw[c] = mrow[c];

  const float* wo = w_out_d + lane;

  float acc = 0.0f;
#pragma unroll
  for (int c = 0; c < 16; ++c) {
    unsigned long long m = mw[c];
    while (m) {
      float w[8];
#pragma unroll
      for (int q = 0; q < 8; ++q) {
        const bool v = (m != 0ull);
        const int idx = v ? __builtin_ctzll(m) : 0;
        m &= m - 1ull;
        const float ld = wo[(size_t)(v ? (c * 64 + idx) : 0) << 6];
        w[q] = v ? ld : 0.0f;
      }
#pragma unroll
      for (int q = 0; q < 8; ++q) acc = __fadd_rn(acc, w[q]);
    }
  }
  out_rec[(size_t)r * NB_OUT + lane] = acc;
}

__global__ __launch_bounds__(256)
void h2_slow(const float* __restrict__ spk_rec,  // [38400,1024]
             const float* __restrict__ w_out_d,  // [1024,64]
             float* __restrict__ out_rec,        // [38400,64]
             int nrows) {
  const int r = blockIdx.x * 4 + (threadIdx.x >> 6);
  const int lane = threadIdx.x & 63;
  if (r >= nrows) return;

  const float* spk = spk_rec + (size_t)r * NB_REC;
  const float* wo  = w_out_d + lane;

  unsigned long long mw[16];
#pragma unroll
  for (int c = 0; c < 16; ++c)
    mw[c] = __ballot(spk[c * 64 + lane] != 0.0f);

  float acc = 0.0f;
#pragma unroll
  for (int c = 0; c < 16; ++c) {
    unsigned long long m = mw[c];
    while (m) {
      float w[8];
#pragma unroll
      for (int q = 0; q < 8; ++q) {
        const bool v = (m != 0ull);
        const int idx = v ? __builtin_ctzll(m) : 0;
        m &= m - 1ull;
        const float ld = wo[(size_t)(v ? (c * 64 + idx) : 0) << 6];
        w[q] = v ? ld : 0.0f;
      }
#pragma unroll
      for (int q = 0; q < 8; ++q) acc = __fadd_rn(acc, w[q]);
    }
  }
  out_rec[(size_t)r * NB_OUT + lane] = acc;
}

// ---------------------------------------------------------------------------
extern "C" void kernel_launch(void* const* d_in, const int* in_sizes, int n_in,
                              void* d_out, int out_size, void* d_ws, size_t ws_size,
                              hipStream_t stream) {
  const float *inputs = nullptr, *noise = nullptr, *w_ff = nullptr,
              *w_rec = nullptr, *w_out = nullptr, *d_sign = nullptr;
  for (int i = 0; i < n_in; ++i) {
    switch (in_sizes[i]) {
      case SZ_INPUTS: inputs = (const float*)d_in[i]; break;
      case SZ_NOISE:  noise  = (const float*)d_in[i]; break;
      case SZ_WFF:    w_ff   = (const float*)d_in[i]; break;
      case SZ_WREC:   w_rec  = (const float*)d_in[i]; break;
      case SZ_WOUT:   w_out  = (const float*)d_in[i]; break;
      case SZ_DSIGN:  d_sign = (const float*)d_in[i]; break;
      default: break;
    }
  }

  float* out = (float*)d_out;

  const size_t WREC_ELEMS = (size_t)WREC_ROWS * NB_REC;
  const size_t WREC_BYTES = WREC_ELEMS * sizeof(float);             // 4.2 MB
  const size_t GWS_BYTES  = (size_t)NROWS * 16 * 8;                 // 4.9 MB
  const size_t INFF_BYTES = (size_t)NROWS * NB_REC * sizeof(float); // 157 MB

  const size_t need_fast = WREC_BYTES + GWS_BYTES + INFF_BYTES;
  const size_t need_slow = WREC_BYTES + INFF_BYTES;

  float sentinel = 0.0f;
  if (!inputs || !noise || !w_ff || !w_rec || !w_out || !d_sign) {
    sentinel = 300.0f;
  } else if (out_size != OUT_TOTAL) {
    sentinel = 700.0f;
  } else if (need_slow > ws_size) {
    sentinel = 500.0f + (float)(ws_size >> 20);
  }

  if (sentinel != 0.0f) {
    sentinel_kernel<<<1, 1, 0, stream>>>(out, sentinel);
    return;
  }

  const bool fast = (need_fast <= ws_size);

  float* out_rec = out + OUT_REC_OFF;
  float* spk_rec = out + SPK_REC_OFF;
  float* o_wrecd = out + WRECD_OFF;
  float* o_woutd = out + WOUTD_OFF;
  float* o_wff   = out + WFF_OFF;

  float* f_wrecd = (float*)d_ws;
  unsigned long long* gws =
      fast ? (unsigned long long*)(f_wrecd + WREC_ELEMS) : nullptr;
  float* inff = fast ? (float*)(gws + (size_t)NROWS * 16)
                     : (f_wrecd + WREC_ELEMS);

  {
    int total = NB_REC * NB_REC + NB_REC * NB_OUT + NB_IN * NB_REC + NB_REC;
    int blocks = (total + 255) / 256;
    weights_kernel<<<blocks, 256, 0, stream>>>(w_rec, w_out, w_ff, d_sign,
                                               f_wrecd,
                                               o_wrecd, o_woutd, o_wff);
  }

  {
    dim3 ggrid(NROWS / 16, NB_REC / 512);   // 2400 x 2
    inff_einsum16<<<ggrid, 256, 0, stream>>>(inputs, w_ff, inff);
  }

  rnn_kernel<<<BATCH, 1024, 0, stream>>>(inff, noise, f_wrecd, spk_rec, gws);

  if (fast) {
    h2_fast<<<(NROWS + 3) / 4, 256, 0, stream>>>(gws, o_woutd, out_rec, NROWS);
  } else {
    h2_slow<<<(NROWS + 3) / 4, 256, 0, stream>>>(spk_rec, o_woutd,
                                                 out_rec, NROWS);
  }
}

// Round 16
// 2000.341 us; speedup vs baseline: 10.5386x; 1.0303x over previous
//
#include <hip/hip_runtime.h>

// ---------------------------------------------------------------------------
// SpikeRNN — r16: r15 (passing, 2060us) with ONE value-preserving change:
// non-temporal (nt) hints on all STREAMING accesses (inff/noise loads,
// spk_rec/gws/out stores) so the 470MB/dispatch stream stops evicting the
// 4MB w_rec from L2 (r15 FETCH=682MB vs 314MB of true stream input =>
// ~368MB of w_rec HBM re-fetch). No computed bit changes.
// Packed-FP32 remains BANNED (r11+r14). rnn structure verbatim r13/r15.
// ---------------------------------------------------------------------------

constexpr int NB_IN  = 256;
constexpr int NB_REC = 1024;
constexpr int NB_OUT = 64;
constexpr int BATCH  = 128;
constexpr int NB_STEPS = 300;
constexpr int TSTEPS = NB_STEPS - 1;

constexpr float ALPHA_F = (float)0.8187307530779818;  // f32(exp(-0.2))
constexpr float BETA_F  = (float)0.9048374180359595;  // f32(exp(-0.1))

// d_out element offsets (f32 elements)
constexpr size_t OUT_REC_OFF = 0;
constexpr size_t SPK_REC_OFF = (size_t)BATCH * NB_STEPS * NB_OUT;
constexpr size_t WRECD_OFF   = SPK_REC_OFF + (size_t)BATCH * NB_STEPS * NB_REC;
constexpr size_t WOUTD_OFF   = WRECD_OFF + (size_t)NB_REC * NB_REC;
constexpr size_t WFF_OFF     = WOUTD_OFF + (size_t)NB_REC * NB_OUT;
constexpr int    OUT_TOTAL   = 43155456;

constexpr int SZ_INPUTS = BATCH * NB_STEPS * NB_IN;   // 9,830,400
constexpr int SZ_NOISE  = BATCH * NB_STEPS * NB_REC;  // 39,321,600
constexpr int SZ_WFF    = NB_IN * NB_REC;             // 262,144
constexpr int SZ_WREC   = NB_REC * NB_REC;            // 1,048,576
constexpr int SZ_WOUT   = NB_REC * NB_OUT;            // 65,536
constexpr int SZ_DSIGN  = NB_REC;                     // 1,024

constexpr int WREC_ROWS = NB_REC + 1;                 // +1 zero row (pad idx)
constexpr int NROWS     = BATCH * NB_STEPS;           // 38400

__global__ void sentinel_kernel(float* out, float v) { out[0] = v; }

// ---------------------------------------------------------------------------
// Dale weights -> ws f32 [1025,1024] (+zero row) and d_out copies. (r13)
// ---------------------------------------------------------------------------
__global__ void weights_kernel(const float* __restrict__ w_rec,
                               const float* __restrict__ w_out,
                               const float* __restrict__ w_ff,
                               const float* __restrict__ d_sign,
                               float* __restrict__ f_wrecd,   // [1025,1024] ws
                               float* __restrict__ o_wrecd,
                               float* __restrict__ o_woutd,
                               float* __restrict__ o_wff) {
  int idx = blockIdx.x * blockDim.x + threadIdx.x;
  if (idx < NB_REC * NB_REC) {
    int i = idx >> 10;
    float v = d_sign[i] * fabsf(w_rec[idx]);
    f_wrecd[idx] = v;
    o_wrecd[idx] = v;
    return;
  }
  int idx2 = idx - NB_REC * NB_REC;
  if (idx2 < NB_REC * NB_OUT) {
    int i = idx2 >> 6;
    o_woutd[idx2] = d_sign[i] * fabsf(w_out[idx2]);
    return;
  }
  int idx3 = idx2 - NB_REC * NB_OUT;
  if (idx3 < NB_IN * NB_REC) {
    o_wff[idx3] = w_ff[idx3];
    return;
  }
  int idx4 = idx3 - NB_IN * NB_REC;
  if (idx4 < NB_REC) {
    f_wrecd[(size_t)NB_REC * NB_REC + idx4] = 0.0f;   // zero row 1024
  }
}

// ---------------------------------------------------------------------------
// einsum16 (r15, passing) + nt hints on streaming A loads / C stores.
// Arithmetic chain unchanged: ascending c, __fadd_rn/__fmul_rn, no FMA.
// ---------------------------------------------------------------------------
__global__ __launch_bounds__(256)
void inff_einsum16(const float* __restrict__ A,    // [38400,256]
                   const float* __restrict__ Bw,   // [256,1024]
                   float* __restrict__ C) {        // [38400,1024]
  const int r0 = blockIdx.x * 16;
  const int tid = threadIdx.x;
  const int d = blockIdx.y * 512 + 2 * tid;        // column pair

  __shared__ float a_s[NB_IN][20];   // [c][rr], rows 80B (16B-aligned)

#pragma unroll
  for (int k = 0; k < 16; ++k) {
    a_s[tid][k] = __builtin_nontemporal_load(&A[(size_t)(r0 + k) * NB_IN + tid]);
  }
  __syncthreads();

  float accL[16], accR[16];
#pragma unroll
  for (int rr = 0; rr < 16; ++rr) { accL[rr] = 0.0f; accR[rr] = 0.0f; }

  const float* bw = Bw + d;
  for (int c = 0; c < NB_IN; ++c) {
    const float2 w2 = *reinterpret_cast<const float2*>(bw + (size_t)c * NB_REC);
    const float4 qa = *reinterpret_cast<const float4*>(&a_s[c][0]);
    const float4 qb = *reinterpret_cast<const float4*>(&a_s[c][4]);
    const float4 qc = *reinterpret_cast<const float4*>(&a_s[c][8]);
    const float4 qd = *reinterpret_cast<const float4*>(&a_s[c][12]);
    const float av[16] = {qa.x, qa.y, qa.z, qa.w, qb.x, qb.y, qb.z, qb.w,
                          qc.x, qc.y, qc.z, qc.w, qd.x, qd.y, qd.z, qd.w};
#pragma unroll
    for (int rr = 0; rr < 16; ++rr) {
      accL[rr] = __fadd_rn(accL[rr], __fmul_rn(av[rr], w2.x));
      accR[rr] = __fadd_rn(accR[rr], __fmul_rn(av[rr], w2.y));
    }
  }

#pragma unroll
  for (int rr = 0; rr < 16; ++rr) {
    float* cp = C + (size_t)(r0 + rr) * NB_REC + d;
    __builtin_nontemporal_store(accL[rr], cp + 0);
    __builtin_nontemporal_store(accR[rr], cp + 1);
  }
}

// ---------------------------------------------------------------------------
// 299-step recurrence — r13/r15 structure verbatim; nt hints on streaming
// inff/noise loads and spk_rec/gws stores (w_rec gather loads stay cached).
// ---------------------------------------------------------------------------
__global__ __launch_bounds__(1024, 1)
void rnn_kernel(const float* __restrict__ inff,    // [128,300,1024]
                const float* __restrict__ noise,   // [128,300,1024]
                const float* __restrict__ w_rec_d, // [1025,1024] f32, ws
                float* __restrict__ spk_rec,       // [128,300,1024]
                unsigned long long* __restrict__ gws) {  // [38400][16] or null
  const int b = blockIdx.x;
  const int j = threadIdx.x;
  const int lane = j & 63;
  const int wv = j >> 6;       // wave 0..15

  __shared__ unsigned s_mask[2][32];
  __shared__ uint4 soff4[16][272];   // per-wave 1088 u32 byte offsets

  unsigned* soffw = (unsigned*)soff4[wv];
  const uint4* soff4w = soff4[wv];

  float syn = 0.0f, mem = 0.0f;
  int rst1 = 0, rst2 = 0;

  __builtin_nontemporal_store(0.0f,
      &spk_rec[((size_t)b * NB_STEPS) * NB_REC + j]);

  const char* wbase = (const char*)w_rec_d;
  const unsigned jb = (unsigned)(j << 2);

  float inf = __builtin_nontemporal_load(
      &inff[((size_t)b * NB_STEPS) * NB_REC + j]);
  float nz = __builtin_nontemporal_load(
      &noise[((size_t)b * NB_STEPS) * NB_REC + j]);

  for (int t = 0; t < TSTEPS; ++t) {
    const int p = t & 1;
    const size_t row = (size_t)b * NB_STEPS + t;

    const float mem_eff = (rst1 | rst2) ? 0.0f : mem;
    const int spike = (__fsub_rn(mem_eff, 1.0f) > 0.0f) ? 1 : 0;

    const unsigned long long msk = __ballot(spike);
    if (lane == 0) {
      s_mask[p][2 * wv]     = (unsigned)msk;
      s_mask[p][2 * wv + 1] = (unsigned)(msk >> 32);
      if (gws) __builtin_nontemporal_store(msk, &gws[(row + 1) * 16 + wv]);
    }

    __builtin_nontemporal_store((float)spike,
        &spk_rec[(row + 1) * NB_REC + j]);
    const float infn = __builtin_nontemporal_load(
        &inff[(row + 1) * NB_REC + j]);
    const float nzn = __builtin_nontemporal_load(
        &noise[(row + 1) * NB_REC + j]);

    __syncthreads();  // (B) masks complete; prev-iter offset reads long done

    const unsigned m0 = (lane < 32) ? s_mask[p][lane] : 0u;
    const int pc = __popc(m0);
    int x = pc;
#pragma unroll
    for (int d = 1; d < 64; d <<= 1) {
      int y = __shfl_up(x, (unsigned)d, 64);
      if (lane >= d) x += y;
    }
    int base = x - pc;           // exclusive prefix
    unsigned m = m0;
    while (m) {
      const int bit = __builtin_ctz(m);
      m &= m - 1;
      soffw[base++] = (unsigned)(((lane << 5) + bit) << 12);
    }
    const int S = __shfl(x, 63);
    if (lane < 48) soffw[S + lane] = (unsigned)(NB_REC << 12);  // pad -> zero row

    auto load16 = [&](int k, float* buf) {
      const uint4 o0 = soff4w[(k >> 2) + 0];
      const uint4 o1 = soff4w[(k >> 2) + 1];
      const uint4 o2 = soff4w[(k >> 2) + 2];
      const uint4 o3 = soff4w[(k >> 2) + 3];
      const unsigned e[16] = {o0.x, o0.y, o0.z, o0.w, o1.x, o1.y, o1.z, o1.w,
                              o2.x, o2.y, o2.z, o2.w, o3.x, o3.y, o3.z, o3.w};
#pragma unroll
      for (int q = 0; q < 16; ++q)
        buf[q] = *reinterpret_cast<const float*>(wbase + (size_t)(e[q] + jb));
    };

    float acc = 0.0f;
    float bufA[16], bufB[16];
    load16(0, bufA);
    for (int k0 = 0; k0 < S; k0 += 32) {
      load16(k0 + 16, bufB);
#pragma unroll
      for (int q = 0; q < 16; ++q) acc = __fadd_rn(acc, bufA[q]);
      load16(k0 + 32, bufA);
#pragma unroll
      for (int q = 0; q < 16; ++q) acc = __fadd_rn(acc, bufB[q]);
    }

    const float new_syn =
        __fadd_rn(__fadd_rn(__fadd_rn(__fmul_rn(ALPHA_F, syn), acc), inf), nz);
    const float new_mem =
        __fsub_rn(__fadd_rn(__fmul_rn(BETA_F, mem_eff), syn), (float)spike);

    syn = new_syn;
    mem = new_mem;
    rst2 = rst1;
    rst1 = spike;
    inf = infn;
    nz = nzn;
  }
}

// ---------------------------------------------------------------------------
// h2_fast / h2_slow — r13 logic; nt on out_rec stores.
// ---------------------------------------------------------------------------
__global__ __launch_bounds__(256)
void h2_fast(const unsigned long long* __restrict__ gws,  // [38400][16]
             const float* __restrict__ w_out_d,           // [1024,64]
             float* __restrict__ out_rec,                 // [38400,64]
             int nrows) {
  const int r = blockIdx.x * 4 + (threadIdx.x >> 6);
  const int lane = threadIdx.x & 63;
  if (r >= nrows) return;
  if (r % NB_STEPS == 0) {
    __builtin_nontemporal_store(0.0f, &out_rec[(size_t)r * NB_OUT + lane]);
    return;
  }

  const unsigned long long* mrow = gws + (size_t)r * 16;
  unsigned long long mw[16];
#pragma unroll
  for (int c = 0; c < 16; ++c) mw[c] = mrow[c];

  const float* wo = w_out_d + lane;

  float acc = 0.0f;
#pragma unroll
  for (int c = 0; c < 16; ++c) {
    unsigned long long m = mw[c];
    while (m) {
      float w[8];
#pragma unroll
      for (int q = 0; q < 8; ++q) {
        const bool v = (m != 0ull);
        const int idx = v ? __builtin_ctzll(m) : 0;
        m &= m - 1ull;
        const float ld = wo[(size_t)(v ? (c * 64 + idx) : 0) << 6];
        w[q] = v ? ld : 0.0f;
      }
#pragma unroll
      for (int q = 0; q < 8; ++q) acc = __fadd_rn(acc, w[q]);
    }
  }
  __builtin_nontemporal_store(acc, &out_rec[(size_t)r * NB_OUT + lane]);
}

__global__ __launch_bounds__(256)
void h2_slow(const float* __restrict__ spk_rec,  // [38400,1024]
             const float* __restrict__ w_out_d,  // [1024,64]
             float* __restrict__ out_rec,        // [38400,64]
             int nrows) {
  const int r = blockIdx.x * 4 + (threadIdx.x >> 6);
  const int lane = threadIdx.x & 63;
  if (r >= nrows) return;

  const float* spk = spk_rec + (size_t)r * NB_REC;
  const float* wo  = w_out_d + lane;

  unsigned long long mw[16];
#pragma unroll
  for (int c = 0; c < 16; ++c)
    mw[c] = __ballot(spk[c * 64 + lane] != 0.0f);

  float acc = 0.0f;
#pragma unroll
  for (int c = 0; c < 16; ++c) {
    unsigned long long m = mw[c];
    while (m) {
      float w[8];
#pragma unroll
      for (int q = 0; q < 8; ++q) {
        const bool v = (m != 0ull);
        const int idx = v ? __builtin_ctzll(m) : 0;
        m &= m - 1ull;
        const float ld = wo[(size_t)(v ? (c * 64 + idx) : 0) << 6];
        w[q] = v ? ld : 0.0f;
      }
#pragma unroll
      for (int q = 0; q < 8; ++q) acc = __fadd_rn(acc, w[q]);
    }
  }
  out_rec[(size_t)r * NB_OUT + lane] = acc;
}

// ---------------------------------------------------------------------------
extern "C" void kernel_launch(void* const* d_in, const int* in_sizes, int n_in,
                              void* d_out, int out_size, void* d_ws, size_t ws_size,
                              hipStream_t stream) {
  const float *inputs = nullptr, *noise = nullptr, *w_ff = nullptr,
              *w_rec = nullptr, *w_out = nullptr, *d_sign = nullptr;
  for (int i = 0; i < n_in; ++i) {
    switch (in_sizes[i]) {
      case SZ_INPUTS: inputs = (const float*)d_in[i]; break;
      case SZ_NOISE:  noise  = (const float*)d_in[i]; break;
      case SZ_WFF:    w_ff   = (const float*)d_in[i]; break;
      case SZ_WREC:   w_rec  = (const float*)d_in[i]; break;
      case SZ_WOUT:   w_out  = (const float*)d_in[i]; break;
      case SZ_DSIGN:  d_sign = (const float*)d_in[i]; break;
      default: break;
    }
  }

  float* out = (float*)d_out;

  const size_t WREC_ELEMS = (size_t)WREC_ROWS * NB_REC;
  const size_t WREC_BYTES = WREC_ELEMS * sizeof(float);             // 4.2 MB
  const size_t GWS_BYTES  = (size_t)NROWS * 16 * 8;                 // 4.9 MB
  const size_t INFF_BYTES = (size_t)NROWS * NB_REC * sizeof(float); // 157 MB

  const size_t need_fast = WREC_BYTES + GWS_BYTES + INFF_BYTES;
  const size_t need_slow = WREC_BYTES + INFF_BYTES;

  float sentinel = 0.0f;
  if (!inputs || !noise || !w_ff || !w_rec || !w_out || !d_sign) {
    sentinel = 300.0f;
  } else if (out_size != OUT_TOTAL) {
    sentinel = 700.0f;
  } else if (need_slow > ws_size) {
    sentinel = 500.0f + (float)(ws_size >> 20);
  }

  if (sentinel != 0.0f) {
    sentinel_kernel<<<1, 1, 0, stream>>>(out, sentinel);
    return;
  }

  const bool fast = (need_fast <= ws_size);

  float* out_rec = out + OUT_REC_OFF;
  float* spk_rec = out + SPK_REC_OFF;
  float* o_wrecd = out + WRECD_OFF;
  float* o_woutd = out + WOUTD_OFF;
  float* o_wff   = out + WFF_OFF;

  float* f_wrecd = (float*)d_ws;
  unsigned long long* gws =
      fast ? (unsigned long long*)(f_wrecd + WREC_ELEMS) : nullptr;
  float* inff = fast ? (float*)(gws + (size_t)NROWS * 16)
                     : (f_wrecd + WREC_ELEMS);

  {
    int total = NB_REC * NB_REC + NB_REC * NB_OUT + NB_IN * NB_REC + NB_REC;
    int blocks = (total + 255) / 256;
    weights_kernel<<<blocks, 256, 0, stream>>>(w_rec, w_out, w_ff, d_sign,
                                               f_wrecd,
                                               o_wrecd, o_woutd, o_wff);
  }

  {
    dim3 ggrid(NROWS / 16, NB_REC / 512);   // 2400 x 2
    inff_einsum16<<<ggrid, 256, 0, stream>>>(inputs, w_ff, inff);
  }

  rnn_kernel<<<BATCH, 1024, 0, stream>>>(inff, noise, f_wrecd, spk_rec, gws);

  if (fast) {
    h2_fast<<<(NROWS + 3) / 4, 256, 0, stream>>>(gws, o_woutd, out_rec, NROWS);
  } else {
    h2_slow<<<(NROWS + 3) / 4, 256, 0, stream>>>(spk_rec, o_woutd,
                                                 out_rec, NROWS);
  }
}